// Round 1
// baseline (618.614 us; speedup 1.0000x reference)
//
#include <hip/hip_runtime.h>
#include <hip/hip_bf16.h>
#include <math.h>

#define TT 256          // T
#define EE 128          // E
#define TJ 16           // j-tile

__device__ __forceinline__ float silu_f(float x) {
    return x / (1.0f + __expf(-x));
}

// ---------------- Phase A: projections ----------------
__global__ __launch_bounds__(256) void phaseA_kernel(
    const float* __restrict__ query, const float* __restrict__ velocity,
    const float* __restrict__ Wq, const float* __restrict__ bq,
    const float* __restrict__ Wk, const float* __restrict__ bk,
    const float* __restrict__ Wv, const float* __restrict__ bv,
    const float* __restrict__ Wvel, const float* __restrict__ bvel,
    float* __restrict__ qs_ws, float* __restrict__ kk_ws,
    float* __restrict__ vproj_ws, float* __restrict__ veldot_ws,
    float* __restrict__ w3_ws) {
    const int row = blockIdx.x;           // b*T + i
    const int t = threadIdx.x;
    __shared__ float sIn[EE];
    __shared__ float sVel[3 * EE];
    __shared__ float sVelp[3 * 384];
    if (t < EE) sIn[t] = query[(size_t)row * EE + t];
    for (int idx = t; idx < 3 * EE; idx += 256)
        sVel[idx] = velocity[(size_t)row * 3 * EE + idx];
    __syncthreads();

    // q (128), k (128), v (384) projections: 640 output columns
    for (int o = t; o < 640; o += 256) {
        if (o < 128) {
            int c = o;
            float acc = bq[c];
#pragma unroll 8
            for (int r = 0; r < 128; ++r) acc = fmaf(sIn[r], Wq[r * 128 + c], acc);
            qs_ws[(size_t)row * 128 + c] = acc * 0.25f;   // * d^-0.5
        } else if (o < 256) {
            int c = o - 128;
            float acc = bk[c];
#pragma unroll 8
            for (int r = 0; r < 128; ++r) acc = fmaf(sIn[r], Wk[r * 128 + c], acc);
            kk_ws[(size_t)row * 128 + c] = acc;
        } else {
            int c = o - 256;
            float acc = bv[c];
#pragma unroll 8
            for (int r = 0; r < 128; ++r) acc = fmaf(sIn[r], Wv[r * 384 + c], acc);
            vproj_ws[(size_t)row * 384 + c] = acc;
        }
    }
    // velp = velocity @ Wvel + bvel  (3 spatial rows share weight column)
    for (int c = t; c < 384; c += 256) {
        float a0 = bvel[c], a1 = a0, a2 = a0;
#pragma unroll 8
        for (int r = 0; r < 128; ++r) {
            float w = Wvel[r * 384 + c];
            a0 = fmaf(sVel[r], w, a0);
            a1 = fmaf(sVel[128 + r], w, a1);
            a2 = fmaf(sVel[256 + r], w, a2);
        }
        sVelp[0 * 384 + c] = a0;
        sVelp[1 * 384 + c] = a1;
        sVelp[2 * 384 + c] = a2;
    }
    __syncthreads();
    if (t < 128) {
        int c = t;
        float vd = 0.f;
#pragma unroll
        for (int s = 0; s < 3; ++s)
            vd += sVelp[s * 384 + c] * sVelp[s * 384 + 128 + c];
        veldot_ws[(size_t)row * 128 + c] = vd;
#pragma unroll
        for (int s = 0; s < 3; ++s)
            w3_ws[((size_t)row * 3 + s) * 128 + c] = sVelp[s * 384 + 256 + c];
    }
}

// ---------------- Phase B: pairwise edge MLP + elementwise attention ----------------
__global__ __launch_bounds__(256, 2) void phaseB_kernel(
    const float* __restrict__ edge_feature, const float* __restrict__ edge_direction,
    const float* __restrict__ cutoff, const float* __restrict__ velocity,
    const float* __restrict__ Wdk, const float* __restrict__ bdk,
    const float* __restrict__ Wdv, const float* __restrict__ bdv,
    const float* __restrict__ qs_ws, const float* __restrict__ kk_ws,
    const float* __restrict__ vproj_ws,
    float* __restrict__ attn_ws, float* __restrict__ vec_ws) {
    const int row = blockIdx.x;            // b*T + i
    const int b = row >> 8;
    const int t = threadIdx.x;

    __shared__ __align__(16) float sEF[TJ][64];    // edge features tile
    __shared__ float sKD[TJ][128];                 // k * silu(dk)
    __shared__ float sGV[TJ][384];                 // vproj * silu(dv)
    __shared__ float sCut[TJ];
    __shared__ float sDir[TJ][3];
    __shared__ float sMrg[128][6];

    // Each thread owns 2 output columns of the [64 x 512] edge MLP; weights in regs.
    // out0 = t  (0..127 -> dk col t ; 128..255 -> dv col t-128)
    // out1 = t + 256    (dv col t+128)
    float w0[64], w1[64];
    float bias0, bias1;
    if (t < 128) {
        bias0 = bdk[t];
#pragma unroll
        for (int r = 0; r < 64; ++r) w0[r] = Wdk[r * 128 + t];
    } else {
        bias0 = bdv[t - 128];
#pragma unroll
        for (int r = 0; r < 64; ++r) w0[r] = Wdv[r * 384 + (t - 128)];
    }
    bias1 = bdv[t + 128];
#pragma unroll
    for (int r = 0; r < 64; ++r) w1[r] = Wdv[r * 384 + (t + 128)];

    const int grp = t >> 7;        // j-half
    const int c = t & 127;         // channel
    const int h = c >> 4;
    const int dd = c & 15;
    const float qsc = qs_ws[(size_t)row * 128 + c] * 0.25f;   // extra /sqrt(d)

    float m = -1e30f, l = 0.f, A = 0.f;
    float v0 = 0.f, v1 = 0.f, v2 = 0.f;

    const size_t ef_base = (size_t)row * TT * 64;
    const size_t cut_base = (size_t)row * TT;
    const size_t dir_base = (size_t)row * TT * 3;

    for (int j0 = 0; j0 < TT; j0 += TJ) {
        {   // stage tile: 16 rows x 64 feats = 256 float4
            const float4* src = (const float4*)(edge_feature + ef_base + (size_t)j0 * 64);
            ((float4*)&sEF[0][0])[t] = src[t];
            if (t < TJ) sCut[t] = cutoff[cut_base + j0 + t];
            if (t < TJ * 3) ((float*)sDir)[t] = edge_direction[dir_base + (size_t)j0 * 3 + t];
        }
        __syncthreads();

        // edge MLP for the 16 j's of this tile
        for (int jj = 0; jj < TJ; ++jj) {
            float a0 = bias0, a1 = bias1;
            const float4* efrow = (const float4*)&sEF[jj][0];
#pragma unroll
            for (int r4 = 0; r4 < 16; ++r4) {
                float4 e4 = efrow[r4];
                a0 = fmaf(e4.x, w0[4 * r4 + 0], a0); a1 = fmaf(e4.x, w1[4 * r4 + 0], a1);
                a0 = fmaf(e4.y, w0[4 * r4 + 1], a0); a1 = fmaf(e4.y, w1[4 * r4 + 1], a1);
                a0 = fmaf(e4.z, w0[4 * r4 + 2], a0); a1 = fmaf(e4.z, w1[4 * r4 + 2], a1);
                a0 = fmaf(e4.w, w0[4 * r4 + 3], a0); a1 = fmaf(e4.w, w1[4 * r4 + 3], a1);
            }
            float s0 = silu_f(a0);
            float s1 = silu_f(a1);
            const int j = j0 + jj;
            if (t < 128) {
                sKD[jj][t] = kk_ws[((size_t)b * TT + j) * 128 + t] * s0;
            } else {
                sGV[jj][t - 128] = vproj_ws[((size_t)b * TT + j) * 384 + (t - 128)] * s0;
            }
            sGV[jj][t + 128] = vproj_ws[((size_t)b * TT + j) * 384 + (t + 128)] * s1;
        }
        __syncthreads();

        // online softmax + attention / vec accumulation, 2 j-groups x 128 channels
        const int jlo = grp * (TJ / 2);
        for (int jj = jlo; jj < jlo + TJ / 2; ++jj) {
            const int j = j0 + jj;
            float kd = sKD[jj][c];
            float a = qsc * kd;
            float m_new = fmaxf(m, a);
            float scale = __expf(m - m_new);
            float p = __expf(a - m_new);
            float cut = sCut[jj];
            float vg = sGV[jj][h * 48 + dd];
            l = l * scale + p;
            A = A * scale + p * cut * vg;
            m = m_new;
            float vp1 = sGV[jj][h * 48 + 16 + dd];
            float vp2 = sGV[jj][h * 48 + 32 + dd];
            if (cut != 0.0f) {
                const float* vel = velocity + ((size_t)b * TT + j) * 3 * 128 + c;
                v0 = fmaf(vel[0],   vp1, fmaf(vp2, sDir[jj][0], v0));
                v1 = fmaf(vel[128], vp1, fmaf(vp2, sDir[jj][1], v1));
                v2 = fmaf(vel[256], vp1, fmaf(vp2, sDir[jj][2], v2));
            }
        }
        __syncthreads();
    }

    // merge the two j-groups
    if (grp == 1) {
        sMrg[c][0] = m;  sMrg[c][1] = l;  sMrg[c][2] = A;
        sMrg[c][3] = v0; sMrg[c][4] = v1; sMrg[c][5] = v2;
    }
    __syncthreads();
    if (grp == 0) {
        float m1 = sMrg[c][0], l1 = sMrg[c][1], A1 = sMrg[c][2];
        float M = fmaxf(m, m1);
        float s0 = __expf(m - M), s1 = __expf(m1 - M);
        float L = l * s0 + l1 * s1;
        float Aa = A * s0 + A1 * s1;
        float attn = (L > 0.f) ? (Aa / L) : 0.f;
        attn_ws[(size_t)row * 128 + c] = attn;
        vec_ws[((size_t)row * 3 + 0) * 128 + c] = v0 + sMrg[c][3];
        vec_ws[((size_t)row * 3 + 1) * 128 + c] = v1 + sMrg[c][4];
        vec_ws[((size_t)row * 3 + 2) * 128 + c] = v2 + sMrg[c][5];
    }
}

// ---------------- Phase C: output projection + epilogue ----------------
__global__ __launch_bounds__(256) void phaseC_kernel(
    const float* __restrict__ Wo, const float* __restrict__ bo,
    const float* __restrict__ attn_ws, const float* __restrict__ veldot_ws,
    const float* __restrict__ w3_ws, const float* __restrict__ vec_ws,
    float* __restrict__ out) {
    const int row = blockIdx.x;
    const int t = threadIdx.x;
    __shared__ float sAttn[128];
    __shared__ float sO[384];
    if (t < 128) sAttn[t] = attn_ws[(size_t)row * 128 + t];
    __syncthreads();
    for (int o = t; o < 384; o += 256) {
        float acc = bo[o];
#pragma unroll 8
        for (int r = 0; r < 128; ++r) acc = fmaf(sAttn[r], Wo[r * 384 + o], acc);
        sO[o] = acc;
    }
    __syncthreads();
    if (t < 128) {
        int c = t;
        float o1 = sO[c], o2 = sO[128 + c], o3 = sO[256 + c];
        float dx = fmaf(veldot_ws[(size_t)row * 128 + c], o2, o3);
        out[(size_t)row * 128 + c] = dx;
#pragma unroll
        for (int s = 0; s < 3; ++s) {
            size_t idx = ((size_t)row * 3 + s) * 128 + c;
            out[131072 + idx] = fmaf(w3_ws[idx], o1, vec_ws[idx]);
        }
    }
}

extern "C" void kernel_launch(void* const* d_in, const int* in_sizes, int n_in,
                              void* d_out, int out_size, void* d_ws, size_t ws_size,
                              hipStream_t stream) {
    (void)in_sizes; (void)n_in; (void)out_size; (void)ws_size;
    const float* query          = (const float*)d_in[0];
    const float* velocity       = (const float*)d_in[1];
    const float* edge_feature   = (const float*)d_in[2];
    const float* edge_direction = (const float*)d_in[3];
    const float* cutoff         = (const float*)d_in[4];
    const float* Wq   = (const float*)d_in[5];  const float* bq   = (const float*)d_in[6];
    const float* Wk   = (const float*)d_in[7];  const float* bk   = (const float*)d_in[8];
    const float* Wv   = (const float*)d_in[9];  const float* bv   = (const float*)d_in[10];
    const float* Wo   = (const float*)d_in[11]; const float* bo   = (const float*)d_in[12];
    const float* Wvel = (const float*)d_in[13]; const float* bvel = (const float*)d_in[14];
    const float* Wdk  = (const float*)d_in[15]; const float* bdk  = (const float*)d_in[16];
    const float* Wdv  = (const float*)d_in[17]; const float* bdv  = (const float*)d_in[18];

    float* ws        = (float*)d_ws;
    float* qs_ws     = ws;              // 131072
    float* kk_ws     = ws + 131072;     // 131072
    float* vproj_ws  = ws + 262144;     // 393216
    float* veldot_ws = ws + 655360;     // 131072
    float* w3_ws     = ws + 786432;     // 393216
    float* attn_ws   = ws + 1179648;    // 131072
    float* vec_ws    = ws + 1310720;    // 393216

    float* out = (float*)d_out;

    hipLaunchKernelGGL(phaseA_kernel, dim3(1024), dim3(256), 0, stream,
        query, velocity, Wq, bq, Wk, bk, Wv, bv, Wvel, bvel,
        qs_ws, kk_ws, vproj_ws, veldot_ws, w3_ws);
    hipLaunchKernelGGL(phaseB_kernel, dim3(1024), dim3(256), 0, stream,
        edge_feature, edge_direction, cutoff, velocity,
        Wdk, bdk, Wdv, bdv, qs_ws, kk_ws, vproj_ws, attn_ws, vec_ws);
    hipLaunchKernelGGL(phaseC_kernel, dim3(1024), dim3(256), 0, stream,
        Wo, bo, attn_ws, veldot_ws, w3_ws, vec_ws, out);
}

// Round 2
// 291.481 us; speedup vs baseline: 2.1223x; 2.1223x over previous
//
#include <hip/hip_runtime.h>
#include <hip/hip_bf16.h>
#include <math.h>

#define TT 256          // T
#define EE 128          // E
#define TJ 16           // j-tile
#define GSTRIDE 516     // sGate row stride in floats (padded: 516%32=4 banks/row shift)

typedef __attribute__((ext_vector_type(8))) short short8v;
typedef __attribute__((ext_vector_type(4))) short short4v;
typedef __attribute__((ext_vector_type(4))) float f32x4;

__device__ __forceinline__ float silu_f(float x) {
    return x / (1.0f + __expf(-x));
}

__device__ __forceinline__ unsigned short f2bf(float f) {
    union { float f; unsigned u; } x; x.f = f;
    unsigned r = (x.u + 0x7FFFu + ((x.u >> 16) & 1u)) >> 16;
    return (unsigned short)r;
}

// ---------------- Phase A: projections ----------------
__global__ __launch_bounds__(256) void phaseA_kernel(
    const float* __restrict__ query, const float* __restrict__ velocity,
    const float* __restrict__ Wq, const float* __restrict__ bq,
    const float* __restrict__ Wk, const float* __restrict__ bk,
    const float* __restrict__ Wv, const float* __restrict__ bv,
    const float* __restrict__ Wvel, const float* __restrict__ bvel,
    float* __restrict__ qs_ws, float* __restrict__ kk_ws,
    float* __restrict__ vproj_ws, float* __restrict__ veldot_ws,
    float* __restrict__ w3_ws) {
    const int row = blockIdx.x;           // b*T + i
    const int t = threadIdx.x;
    __shared__ float sIn[EE];
    __shared__ float sVel[3 * EE];
    __shared__ float sVelp[3 * 384];
    if (t < EE) sIn[t] = query[(size_t)row * EE + t];
    for (int idx = t; idx < 3 * EE; idx += 256)
        sVel[idx] = velocity[(size_t)row * 3 * EE + idx];
    __syncthreads();

    for (int o = t; o < 640; o += 256) {
        if (o < 128) {
            int c = o;
            float acc = bq[c];
#pragma unroll 8
            for (int r = 0; r < 128; ++r) acc = fmaf(sIn[r], Wq[r * 128 + c], acc);
            qs_ws[(size_t)row * 128 + c] = acc * 0.25f;   // * d^-0.5
        } else if (o < 256) {
            int c = o - 128;
            float acc = bk[c];
#pragma unroll 8
            for (int r = 0; r < 128; ++r) acc = fmaf(sIn[r], Wk[r * 128 + c], acc);
            kk_ws[(size_t)row * 128 + c] = acc;
        } else {
            int c = o - 256;
            float acc = bv[c];
#pragma unroll 8
            for (int r = 0; r < 128; ++r) acc = fmaf(sIn[r], Wv[r * 384 + c], acc);
            vproj_ws[(size_t)row * 384 + c] = acc;
        }
    }
    for (int c = t; c < 384; c += 256) {
        float a0 = bvel[c], a1 = a0, a2 = a0;
#pragma unroll 8
        for (int r = 0; r < 128; ++r) {
            float w = Wvel[r * 384 + c];
            a0 = fmaf(sVel[r], w, a0);
            a1 = fmaf(sVel[128 + r], w, a1);
            a2 = fmaf(sVel[256 + r], w, a2);
        }
        sVelp[0 * 384 + c] = a0;
        sVelp[1 * 384 + c] = a1;
        sVelp[2 * 384 + c] = a2;
    }
    __syncthreads();
    if (t < 128) {
        int c = t;
        float vd = 0.f;
#pragma unroll
        for (int s = 0; s < 3; ++s)
            vd += sVelp[s * 384 + c] * sVelp[s * 384 + 128 + c];
        veldot_ws[(size_t)row * 128 + c] = vd;
#pragma unroll
        for (int s = 0; s < 3; ++s)
            w3_ws[((size_t)row * 3 + s) * 128 + c] = sVelp[s * 384 + 256 + c];
    }
}

// ---------------- Phase B: MFMA edge MLP + elementwise attention ----------------
__global__ __launch_bounds__(256, 4) void phaseB_kernel(
    const float* __restrict__ edge_feature, const float* __restrict__ edge_direction,
    const float* __restrict__ cutoff, const float* __restrict__ velocity,
    const float* __restrict__ Wdk, const float* __restrict__ bdk,
    const float* __restrict__ Wdv, const float* __restrict__ bdv,
    const float* __restrict__ qs_ws, const float* __restrict__ kk_ws,
    const float* __restrict__ vproj_ws,
    float* __restrict__ attn_ws, float* __restrict__ vec_ws) {
    const int row = blockIdx.x;            // b*T + i
    const int b = row >> 8;
    const int t = threadIdx.x;
    const int wave = t >> 6;
    const int lane = t & 63;
    const int lrow = lane >> 4;            // 0..3
    const int lcol = lane & 15;            // 0..15

    __shared__ __align__(16) unsigned char sEFb[16 * 128];   // bf16 EF tile, XOR-swizzled
    __shared__ float sGate[16 * GSTRIDE];                    // silu(dk)|silu(dv) per tile
    __shared__ float sCut[TJ];
    __shared__ float sDir[TJ][3];
    __shared__ float sMrg[128][5];

    // --- B fragments (weights) in registers: each wave owns 128 output cols ---
    // wave 0 -> dk cols 0..127 (gate cols 0..127)
    // wave w>=1 -> dv cols (w-1)*128.. (gate cols 128+(w-1)*128..)
    const float* Wsel;
    const float* Bsel;
    int wstride, colbase, gatebase;
    if (wave == 0) { Wsel = Wdk; Bsel = bdk; wstride = 128; colbase = 0; gatebase = 0; }
    else { Wsel = Wdv; Bsel = bdv; wstride = 384; colbase = (wave - 1) * 128; gatebase = 128 + (wave - 1) * 128; }

    short8v bw[16];          // [n][kh] -> bw[n*2+kh]
    float biasv[8];
#pragma unroll
    for (int n = 0; n < 8; ++n) {
        const int col = colbase + n * 16 + lcol;
        biasv[n] = Bsel[col];
#pragma unroll
        for (int kh = 0; kh < 2; ++kh) {
            short8v f;
#pragma unroll
            for (int e = 0; e < 8; ++e) {
                const int k = kh * 32 + lrow * 8 + e;
                f[e] = (short)f2bf(Wsel[k * wstride + col]);
            }
            bw[n * 2 + kh] = f;
        }
    }

    const int grp = t >> 7;        // j-half for attention phase
    const int c = t & 127;         // channel
    const int h = c >> 4;
    const int dd = c & 15;
    const float qsc = qs_ws[(size_t)row * 128 + c] * 0.25f;   // extra /sqrt(d)

    float l = 0.f, A = 0.f;
    float v0 = 0.f, v1 = 0.f, v2 = 0.f;

    const size_t ef_base = (size_t)row * TT * 64;
    const size_t cut_base = (size_t)row * TT;
    const size_t dir_base = (size_t)row * TT * 3;

    for (int j0 = 0; j0 < TT; j0 += TJ) {
        {   // stage tile as bf16 with XOR swizzle: 16 rows x 64 feats
            const float4 e4 = ((const float4*)(edge_feature + ef_base + (size_t)j0 * 64))[t];
            const int erow = t >> 4;            // j within tile
            const int kq = t & 15;              // 4 feats at k=kq*4
            short4v pk;
            pk[0] = (short)f2bf(e4.x); pk[1] = (short)f2bf(e4.y);
            pk[2] = (short)f2bf(e4.z); pk[3] = (short)f2bf(e4.w);
            const int byte = (kq * 8) ^ ((erow & 7) << 4);
            *(short4v*)(sEFb + erow * 128 + byte) = pk;
            if (t < TJ) sCut[t] = cutoff[cut_base + j0 + t];
            if (t < TJ * 3) ((float*)sDir)[t] = edge_direction[dir_base + (size_t)j0 * 3 + t];
        }
        __syncthreads();

        // --- MFMA: [16 j x 64 R] @ [64 x 512] -> silu -> sGate ---
        {
            const int arow = lcol;   // A-fragment row (= j index)
            const int swz = (arow & 7) << 4;
            const short8v a0 = *(const short8v*)(sEFb + arow * 128 + ((lrow * 16) ^ swz));
            const short8v a1 = *(const short8v*)(sEFb + arow * 128 + ((64 + lrow * 16) ^ swz));
#pragma unroll
            for (int n = 0; n < 8; ++n) {
                const float bv0 = biasv[n];
                f32x4 acc = {bv0, bv0, bv0, bv0};
                acc = __builtin_amdgcn_mfma_f32_16x16x32_bf16(a0, bw[n * 2 + 0], acc, 0, 0, 0);
                acc = __builtin_amdgcn_mfma_f32_16x16x32_bf16(a1, bw[n * 2 + 1], acc, 0, 0, 0);
                const int gcol = gatebase + n * 16 + lcol;
#pragma unroll
                for (int r = 0; r < 4; ++r) {
                    const int jj = lrow * 4 + r;          // C/D row = j index
                    sGate[jj * GSTRIDE + gcol] = silu_f(acc[r]);
                }
            }
        }
        __syncthreads();

        // --- attention accumulation: 2 j-groups x 128 channels ---
        const int jlo = grp * (TJ / 2);
#pragma unroll
        for (int jj = jlo; jj < jlo + TJ / 2; ++jj) {
            const int j = j0 + jj;
            const float* gate = &sGate[jj * GSTRIDE];
            const float* vp = vproj_ws + ((size_t)b * TT + j) * 384 + h * 48 + dd;
            const float kd = kk_ws[((size_t)b * TT + j) * 128 + c] * gate[c];
            const float p = __expf(qsc * kd);
            const float cut = sCut[jj];
            const float vg  = vp[0]  * gate[128 + h * 48 + dd];
            const float vp1 = vp[16] * gate[128 + h * 48 + 16 + dd];
            const float vp2 = vp[32] * gate[128 + h * 48 + 32 + dd];
            l += p;
            A = fmaf(p * cut, vg, A);
            if (cut != 0.0f) {
                const float* vel = velocity + ((size_t)b * TT + j) * 384 + c;
                v0 = fmaf(vel[0],   vp1, fmaf(vp2, sDir[jj][0], v0));
                v1 = fmaf(vel[128], vp1, fmaf(vp2, sDir[jj][1], v1));
                v2 = fmaf(vel[256], vp1, fmaf(vp2, sDir[jj][2], v2));
            }
        }
        __syncthreads();
    }

    // merge the two j-groups
    if (grp == 1) {
        sMrg[c][0] = l;  sMrg[c][1] = A;
        sMrg[c][2] = v0; sMrg[c][3] = v1; sMrg[c][4] = v2;
    }
    __syncthreads();
    if (grp == 0) {
        const float L = l + sMrg[c][0];
        const float Aa = A + sMrg[c][1];
        const float attn = (L > 0.f) ? (Aa / L) : 0.f;
        attn_ws[(size_t)row * 128 + c] = attn;
        vec_ws[((size_t)row * 3 + 0) * 128 + c] = v0 + sMrg[c][2];
        vec_ws[((size_t)row * 3 + 1) * 128 + c] = v1 + sMrg[c][3];
        vec_ws[((size_t)row * 3 + 2) * 128 + c] = v2 + sMrg[c][4];
    }
}

// ---------------- Phase C: output projection + epilogue ----------------
__global__ __launch_bounds__(256) void phaseC_kernel(
    const float* __restrict__ Wo, const float* __restrict__ bo,
    const float* __restrict__ attn_ws, const float* __restrict__ veldot_ws,
    const float* __restrict__ w3_ws, const float* __restrict__ vec_ws,
    float* __restrict__ out) {
    const int row = blockIdx.x;
    const int t = threadIdx.x;
    __shared__ float sAttn[128];
    __shared__ float sO[384];
    if (t < 128) sAttn[t] = attn_ws[(size_t)row * 128 + t];
    __syncthreads();
    for (int o = t; o < 384; o += 256) {
        float acc = bo[o];
#pragma unroll 8
        for (int r = 0; r < 128; ++r) acc = fmaf(sAttn[r], Wo[r * 384 + o], acc);
        sO[o] = acc;
    }
    __syncthreads();
    if (t < 128) {
        int c = t;
        float o1 = sO[c], o2 = sO[128 + c], o3 = sO[256 + c];
        float dx = fmaf(veldot_ws[(size_t)row * 128 + c], o2, o3);
        out[(size_t)row * 128 + c] = dx;
#pragma unroll
        for (int s = 0; s < 3; ++s) {
            size_t idx = ((size_t)row * 3 + s) * 128 + c;
            out[131072 + idx] = fmaf(w3_ws[idx], o1, vec_ws[idx]);
        }
    }
}

extern "C" void kernel_launch(void* const* d_in, const int* in_sizes, int n_in,
                              void* d_out, int out_size, void* d_ws, size_t ws_size,
                              hipStream_t stream) {
    (void)in_sizes; (void)n_in; (void)out_size; (void)ws_size;
    const float* query          = (const float*)d_in[0];
    const float* velocity       = (const float*)d_in[1];
    const float* edge_feature   = (const float*)d_in[2];
    const float* edge_direction = (const float*)d_in[3];
    const float* cutoff         = (const float*)d_in[4];
    const float* Wq   = (const float*)d_in[5];  const float* bq   = (const float*)d_in[6];
    const float* Wk   = (const float*)d_in[7];  const float* bk   = (const float*)d_in[8];
    const float* Wv   = (const float*)d_in[9];  const float* bv   = (const float*)d_in[10];
    const float* Wo   = (const float*)d_in[11]; const float* bo   = (const float*)d_in[12];
    const float* Wvel = (const float*)d_in[13]; const float* bvel = (const float*)d_in[14];
    const float* Wdk  = (const float*)d_in[15]; const float* bdk  = (const float*)d_in[16];
    const float* Wdv  = (const float*)d_in[17]; const float* bdv  = (const float*)d_in[18];

    float* ws        = (float*)d_ws;
    float* qs_ws     = ws;              // 131072
    float* kk_ws     = ws + 131072;     // 131072
    float* vproj_ws  = ws + 262144;     // 393216
    float* veldot_ws = ws + 655360;     // 131072
    float* w3_ws     = ws + 786432;     // 393216
    float* attn_ws   = ws + 1179648;    // 131072
    float* vec_ws    = ws + 1310720;    // 393216

    float* out = (float*)d_out;

    hipLaunchKernelGGL(phaseA_kernel, dim3(1024), dim3(256), 0, stream,
        query, velocity, Wq, bq, Wk, bk, Wv, bv, Wvel, bvel,
        qs_ws, kk_ws, vproj_ws, veldot_ws, w3_ws);
    hipLaunchKernelGGL(phaseB_kernel, dim3(1024), dim3(256), 0, stream,
        edge_feature, edge_direction, cutoff, velocity,
        Wdk, bdk, Wdv, bdv, qs_ws, kk_ws, vproj_ws, attn_ws, vec_ws);
    hipLaunchKernelGGL(phaseC_kernel, dim3(1024), dim3(256), 0, stream,
        Wo, bo, attn_ws, veldot_ws, w3_ws, vec_ws, out);
}

// Round 3
// 231.690 us; speedup vs baseline: 2.6700x; 1.2581x over previous
//
#include <hip/hip_runtime.h>
#include <hip/hip_bf16.h>
#include <math.h>

#define TT 256          // T
#define EE 128          // E
#define TJ 16           // j-tile

typedef __attribute__((ext_vector_type(8))) short short8v;
typedef __attribute__((ext_vector_type(4))) float f32x4;

__device__ __forceinline__ float silu_f(float x) {
    return x * __builtin_amdgcn_rcpf(1.0f + __expf(-x));
}

__device__ __forceinline__ unsigned short f2bf(float f) {
    union { float f; unsigned u; } x; x.f = f;
    unsigned r = (x.u + 0x7FFFu + ((x.u >> 16) & 1u)) >> 16;
    return (unsigned short)r;
}

__device__ __forceinline__ unsigned cvt_pk_bf16(float lo, float hi) {
    unsigned r;
    asm("v_cvt_pk_bf16_f32 %0, %1, %2" : "=v"(r) : "v"(lo), "v"(hi));
    return r;
}

__device__ __forceinline__ float bflo(unsigned u) { return __uint_as_float(u << 16); }
__device__ __forceinline__ float bfhi(unsigned u) { return __uint_as_float(u & 0xffff0000u); }

// ---------------- Phase A: projections ----------------
__global__ __launch_bounds__(256) void phaseA_kernel(
    const float* __restrict__ query, const float* __restrict__ velocity,
    const float* __restrict__ Wq, const float* __restrict__ bq,
    const float* __restrict__ Wk, const float* __restrict__ bk,
    const float* __restrict__ Wv, const float* __restrict__ bv,
    const float* __restrict__ Wvel, const float* __restrict__ bvel,
    float* __restrict__ qs_ws, float* __restrict__ kk_ws,
    float* __restrict__ vproj_ws, float* __restrict__ veldot_ws,
    float* __restrict__ w3_ws) {
    const int row = blockIdx.x;           // b*T + i
    const int t = threadIdx.x;
    __shared__ float sIn[EE];
    __shared__ float sVel[3 * EE];
    __shared__ float sVelp[3 * 384];
    if (t < EE) sIn[t] = query[(size_t)row * EE + t];
    for (int idx = t; idx < 3 * EE; idx += 256)
        sVel[idx] = velocity[(size_t)row * 3 * EE + idx];
    __syncthreads();

    for (int o = t; o < 640; o += 256) {
        if (o < 128) {
            int c = o;
            float acc = bq[c];
#pragma unroll 8
            for (int r = 0; r < 128; ++r) acc = fmaf(sIn[r], Wq[r * 128 + c], acc);
            qs_ws[(size_t)row * 128 + c] = acc * 0.25f;   // * d^-0.5
        } else if (o < 256) {
            int c = o - 128;
            float acc = bk[c];
#pragma unroll 8
            for (int r = 0; r < 128; ++r) acc = fmaf(sIn[r], Wk[r * 128 + c], acc);
            kk_ws[(size_t)row * 128 + c] = acc;
        } else {
            int c = o - 256;
            float acc = bv[c];
#pragma unroll 8
            for (int r = 0; r < 128; ++r) acc = fmaf(sIn[r], Wv[r * 384 + c], acc);
            vproj_ws[(size_t)row * 384 + c] = acc;
        }
    }
    for (int c = t; c < 384; c += 256) {
        float a0 = bvel[c], a1 = a0, a2 = a0;
#pragma unroll 8
        for (int r = 0; r < 128; ++r) {
            float w = Wvel[r * 384 + c];
            a0 = fmaf(sVel[r], w, a0);
            a1 = fmaf(sVel[128 + r], w, a1);
            a2 = fmaf(sVel[256 + r], w, a2);
        }
        sVelp[0 * 384 + c] = a0;
        sVelp[1 * 384 + c] = a1;
        sVelp[2 * 384 + c] = a2;
    }
    __syncthreads();
    if (t < 128) {
        int c = t;
        float vd = 0.f;
#pragma unroll
        for (int s = 0; s < 3; ++s)
            vd += sVelp[s * 384 + c] * sVelp[s * 384 + 128 + c];
        veldot_ws[(size_t)row * 128 + c] = vd;
#pragma unroll
        for (int s = 0; s < 3; ++s)
            w3_ws[((size_t)row * 3 + s) * 128 + c] = sVelp[s * 384 + 256 + c];
    }
}

// ---------------- Phase B: MFMA edge MLP + elementwise attention ----------------
__global__ __launch_bounds__(256, 4) void phaseB_kernel(
    const float* __restrict__ edge_feature, const float* __restrict__ edge_direction,
    const float* __restrict__ cutoff, const float* __restrict__ velocity,
    const float* __restrict__ Wdk, const float* __restrict__ bdk,
    const float* __restrict__ Wdv, const float* __restrict__ bdv,
    const float* __restrict__ qs_ws, const float* __restrict__ kk_ws,
    const float* __restrict__ vproj_ws,
    float* __restrict__ attn_ws, float* __restrict__ vec_ws) {
    // XCD swizzle: xcd = blk%8 (round-robin dispatch). Give each XCD one batch
    // half so its L2 holds exactly one batch's kk/vproj/velocity (~900 KB).
    const int blk = blockIdx.x;
    const int x = blk & 7;
    const int slot = blk >> 3;            // 0..127
    const int b = x >> 1;
    const int i = ((x & 1) << 7) + slot;
    const int row = b * TT + i;

    const int t = threadIdx.x;
    const int wave = t >> 6;
    const int lane = t & 63;
    const int lrow = lane >> 4;            // 0..3
    const int lcol = lane & 15;            // 0..15

    __shared__ __align__(16) unsigned char sEFb[16 * 128];   // bf16 EF tile, XOR-swizzled
    __shared__ unsigned short sKD[128 * 18];                 // kk*silu(dk), [col][j]
    __shared__ unsigned short sGV[3 * 128 * 18];             // vproj*silu(dv), [plane][c][j]
    __shared__ float sCut[TJ];
    __shared__ float sDirS[TJ * 3];
    __shared__ float sMrg[128][5];

    // --- B fragments (weights) in registers: each wave owns 128 output cols ---
    const float* Wsel;
    const float* Bsel;
    int wstride, colbase;
    if (wave == 0) { Wsel = Wdk; Bsel = bdk; wstride = 128; colbase = 0; }
    else { Wsel = Wdv; Bsel = bdv; wstride = 384; colbase = (wave - 1) * 128; }

    short8v bw[16];          // [n][kh] -> bw[n*2+kh]
    float biasv[8];
#pragma unroll
    for (int n = 0; n < 8; ++n) {
        const int col = colbase + n * 16 + lcol;
        biasv[n] = Bsel[col];
#pragma unroll
        for (int kh = 0; kh < 2; ++kh) {
            short8v f;
#pragma unroll
            for (int e = 0; e < 8; ++e) {
                const int k = kh * 32 + lrow * 8 + e;
                f[e] = (short)f2bf(Wsel[k * wstride + col]);
            }
            bw[n * 2 + kh] = f;
        }
    }

    // gate-source array for the epilogue (same col indexing as weights)
    const float* gsrc = (wave == 0) ? (kk_ws + (size_t)(b * TT) * 128)
                                    : (vproj_ws + (size_t)(b * TT) * 384);
    const int gstride = (wave == 0) ? 128 : 384;

    const int grp = t >> 7;        // j-half for attention phase
    const int c = t & 127;         // channel
    const float qsc = qs_ws[(size_t)row * 128 + c] * 0.25f;   // extra /sqrt(d)

    float l = 0.f, A = 0.f;
    float v0 = 0.f, v1 = 0.f, v2 = 0.f;

    const size_t ef_base = (size_t)row * TT * 64;
    const size_t cut_base = (size_t)row * TT;
    const size_t dir_base = (size_t)row * TT * 3;
    const float* velbase = velocity + (size_t)(b * TT) * 384 + c;

    // initial prefetch (tile 0)
    float4 ef4 = ((const float4*)(edge_feature + ef_base))[t];
    float cutv = (t < TJ) ? cutoff[cut_base + t] : 0.f;
    float dirv = (t < TJ * 3) ? edge_direction[dir_base + t] : 0.f;

    for (int j0 = 0; j0 < TT; j0 += TJ) {
        {   // write staged tile (bf16, XOR swizzle)
            const int erow = t >> 4;
            const int kq = t & 15;
            unsigned plo = cvt_pk_bf16(ef4.x, ef4.y);
            unsigned phi = cvt_pk_bf16(ef4.z, ef4.w);
            const int byteoff = (kq * 8) ^ ((erow & 7) << 4);
            *(int2*)(sEFb + erow * 128 + byteoff) = make_int2((int)plo, (int)phi);
            if (t < TJ) sCut[t] = cutv;
            if (t < TJ * 3) sDirS[t] = dirv;
        }
        __syncthreads();

        // --- MFMA: [16 j x 64 R] @ [64 x 512] -> silu -> product -> LDS ---
        {
            const int arow = lcol;
            const int swzb = (arow & 7) << 4;
            const short8v a0 = *(const short8v*)(sEFb + arow * 128 + ((lrow * 16) ^ swzb));
            const short8v a1 = *(const short8v*)(sEFb + arow * 128 + ((64 + lrow * 16) ^ swzb));
            const int jb = j0 + lrow * 4;
#pragma unroll
            for (int n = 0; n < 8; ++n) {
                const int col = colbase + n * 16 + lcol;
                const float* gp = gsrc + (size_t)jb * gstride + col;
                const float g0 = gp[0];
                const float g1 = gp[gstride];
                const float g2 = gp[2 * gstride];
                const float g3 = gp[3 * gstride];
                f32x4 acc = {biasv[n], biasv[n], biasv[n], biasv[n]};
                acc = __builtin_amdgcn_mfma_f32_16x16x32_bf16(a0, bw[2 * n],     acc, 0, 0, 0);
                acc = __builtin_amdgcn_mfma_f32_16x16x32_bf16(a1, bw[2 * n + 1], acc, 0, 0, 0);
                const float r0 = g0 * silu_f(acc[0]);
                const float r1 = g1 * silu_f(acc[1]);
                const float r2 = g2 * silu_f(acc[2]);
                const float r3 = g3 * silu_f(acc[3]);
                const unsigned w01 = cvt_pk_bf16(r0, r1);
                const unsigned w23 = cvt_pk_bf16(r2, r3);
                unsigned short* dst;
                if (wave == 0) {
                    dst = &sKD[col * 18 + lrow * 4];
                } else {
                    const int plane = (col >> 4) % 3;
                    const int cch = (col / 48) * 16 + lcol;
                    dst = &sGV[plane * 2304 + cch * 18 + lrow * 4];
                }
                *(unsigned*)(dst) = w01;
                *(unsigned*)(dst + 2) = w23;
            }
        }

        // prefetch next tile while products settle / attention runs
        {
            const int jn = (j0 + TJ < TT) ? (j0 + TJ) : 0;
            ef4 = ((const float4*)(edge_feature + ef_base + (size_t)jn * 64))[t];
            cutv = (t < TJ) ? cutoff[cut_base + jn + t] : 0.f;
            dirv = (t < TJ * 3) ? edge_direction[dir_base + (size_t)jn * 3 + t] : 0.f;
        }
        __syncthreads();

        // --- attention accumulation: 2 j-groups x 128 channels, 2 j per step ---
        {
            const int jlo = grp * (TJ / 2);
#pragma unroll
            for (int q = 0; q < 4; ++q) {
                const int jj = jlo + 2 * q;
                const unsigned kd2 = *(const unsigned*)(&sKD[c * 18 + jj]);
                const unsigned vg2 = *(const unsigned*)(&sGV[0 * 2304 + c * 18 + jj]);
                const unsigned p12 = *(const unsigned*)(&sGV[1 * 2304 + c * 18 + jj]);
                const unsigned p22 = *(const unsigned*)(&sGV[2 * 2304 + c * 18 + jj]);
                const float cut0 = sCut[jj];
                const float cut1 = sCut[jj + 1];
                const float p0 = __expf(qsc * bflo(kd2));
                const float p1 = __expf(qsc * bfhi(kd2));
                l += p0 + p1;
                A = fmaf(p0 * cut0, bflo(vg2), A);
                A = fmaf(p1 * cut1, bfhi(vg2), A);
                if (cut0 != 0.0f) {
                    const float* vp = velbase + (size_t)(j0 + jj) * 384;
                    const float w1 = bflo(p12), w2 = bflo(p22);
                    v0 = fmaf(vp[0],   w1, fmaf(w2, sDirS[jj * 3 + 0], v0));
                    v1 = fmaf(vp[128], w1, fmaf(w2, sDirS[jj * 3 + 1], v1));
                    v2 = fmaf(vp[256], w1, fmaf(w2, sDirS[jj * 3 + 2], v2));
                }
                if (cut1 != 0.0f) {
                    const float* vp = velbase + (size_t)(j0 + jj + 1) * 384;
                    const float w1 = bfhi(p12), w2 = bfhi(p22);
                    v0 = fmaf(vp[0],   w1, fmaf(w2, sDirS[jj * 3 + 3], v0));
                    v1 = fmaf(vp[128], w1, fmaf(w2, sDirS[jj * 3 + 4], v1));
                    v2 = fmaf(vp[256], w1, fmaf(w2, sDirS[jj * 3 + 5], v2));
                }
            }
        }
        __syncthreads();
    }

    // merge the two j-groups
    if (grp == 1) {
        sMrg[c][0] = l;  sMrg[c][1] = A;
        sMrg[c][2] = v0; sMrg[c][3] = v1; sMrg[c][4] = v2;
    }
    __syncthreads();
    if (grp == 0) {
        const float L = l + sMrg[c][0];
        const float Aa = A + sMrg[c][1];
        const float attn = (L > 0.f) ? (Aa * __builtin_amdgcn_rcpf(L)) : 0.f;
        attn_ws[(size_t)row * 128 + c] = attn;
        vec_ws[((size_t)row * 3 + 0) * 128 + c] = v0 + sMrg[c][2];
        vec_ws[((size_t)row * 3 + 1) * 128 + c] = v1 + sMrg[c][3];
        vec_ws[((size_t)row * 3 + 2) * 128 + c] = v2 + sMrg[c][4];
    }
}

// ---------------- Phase C: output projection + epilogue ----------------
__global__ __launch_bounds__(256) void phaseC_kernel(
    const float* __restrict__ Wo, const float* __restrict__ bo,
    const float* __restrict__ attn_ws, const float* __restrict__ veldot_ws,
    const float* __restrict__ w3_ws, const float* __restrict__ vec_ws,
    float* __restrict__ out) {
    const int row = blockIdx.x;
    const int t = threadIdx.x;
    __shared__ float sAttn[128];
    __shared__ float sO[384];
    if (t < 128) sAttn[t] = attn_ws[(size_t)row * 128 + t];
    __syncthreads();
    for (int o = t; o < 384; o += 256) {
        float acc = bo[o];
#pragma unroll 8
        for (int r = 0; r < 128; ++r) acc = fmaf(sAttn[r], Wo[r * 384 + o], acc);
        sO[o] = acc;
    }
    __syncthreads();
    if (t < 128) {
        int c = t;
        float o1 = sO[c], o2 = sO[128 + c], o3 = sO[256 + c];
        float dx = fmaf(veldot_ws[(size_t)row * 128 + c], o2, o3);
        out[(size_t)row * 128 + c] = dx;
#pragma unroll
        for (int s = 0; s < 3; ++s) {
            size_t idx = ((size_t)row * 3 + s) * 128 + c;
            out[131072 + idx] = fmaf(w3_ws[idx], o1, vec_ws[idx]);
        }
    }
}

extern "C" void kernel_launch(void* const* d_in, const int* in_sizes, int n_in,
                              void* d_out, int out_size, void* d_ws, size_t ws_size,
                              hipStream_t stream) {
    (void)in_sizes; (void)n_in; (void)out_size; (void)ws_size;
    const float* query          = (const float*)d_in[0];
    const float* velocity       = (const float*)d_in[1];
    const float* edge_feature   = (const float*)d_in[2];
    const float* edge_direction = (const float*)d_in[3];
    const float* cutoff         = (const float*)d_in[4];
    const float* Wq   = (const float*)d_in[5];  const float* bq   = (const float*)d_in[6];
    const float* Wk   = (const float*)d_in[7];  const float* bk   = (const float*)d_in[8];
    const float* Wv   = (const float*)d_in[9];  const float* bv   = (const float*)d_in[10];
    const float* Wo   = (const float*)d_in[11]; const float* bo   = (const float*)d_in[12];
    const float* Wvel = (const float*)d_in[13]; const float* bvel = (const float*)d_in[14];
    const float* Wdk  = (const float*)d_in[15]; const float* bdk  = (const float*)d_in[16];
    const float* Wdv  = (const float*)d_in[17]; const float* bdv  = (const float*)d_in[18];

    float* ws        = (float*)d_ws;
    float* qs_ws     = ws;              // 131072
    float* kk_ws     = ws + 131072;     // 131072
    float* vproj_ws  = ws + 262144;     // 393216
    float* veldot_ws = ws + 655360;     // 131072
    float* w3_ws     = ws + 786432;     // 393216
    float* attn_ws   = ws + 1179648;    // 131072
    float* vec_ws    = ws + 1310720;    // 393216

    float* out = (float*)d_out;

    hipLaunchKernelGGL(phaseA_kernel, dim3(1024), dim3(256), 0, stream,
        query, velocity, Wq, bq, Wk, bk, Wv, bv, Wvel, bvel,
        qs_ws, kk_ws, vproj_ws, veldot_ws, w3_ws);
    hipLaunchKernelGGL(phaseB_kernel, dim3(1024), dim3(256), 0, stream,
        edge_feature, edge_direction, cutoff, velocity,
        Wdk, bdk, Wdv, bdv, qs_ws, kk_ws, vproj_ws, attn_ws, vec_ws);
    hipLaunchKernelGGL(phaseC_kernel, dim3(1024), dim3(256), 0, stream,
        Wo, bo, attn_ws, veldot_ws, w3_ws, vec_ws, out);
}